// Round 1
// baseline (375.706 us; speedup 1.0000x reference)
//
#include <hip/hip_runtime.h>
#include <hip/hip_bf16.h>

// B=2, S=2048, D=1024, H=16, dh=64.  All compute bf16 MFMA, fp32 accum/softmax.
// ws layout (unsigned short elems): xb[4M] wt[4M] qb[4M] kb[4M] vt[4M] cb[4M] = 48MB.

typedef short short8  __attribute__((ext_vector_type(8)));
typedef short short4v __attribute__((ext_vector_type(4)));
typedef float f32x4   __attribute__((ext_vector_type(4)));

#define GLOB_AS __attribute__((address_space(1)))
#define LDS_AS  __attribute__((address_space(3)))

__device__ __forceinline__ unsigned short f2b(float f) {
  union { float f; unsigned u; } v; v.f = f;
  return (unsigned short)((v.u + 0x7fffu + ((v.u >> 16) & 1u)) >> 16);
}

__device__ __forceinline__ f32x4 mfma16(short8 a, short8 b, f32x4 c) {
  return __builtin_amdgcn_mfma_f32_16x16x32_bf16(a, b, c, 0, 0, 0);
}

__device__ __forceinline__ void gload_lds16(const unsigned short* g, unsigned short* l) {
  __builtin_amdgcn_global_load_lds((const GLOB_AS void*)g, (LDS_AS void*)l, 16, 0, 0);
}

// ---------------- f32 -> bf16 elementwise (x) ----------------
__global__ void cvt_x_kernel(const float* __restrict__ in, unsigned short* __restrict__ out) {
  int i = (blockIdx.x * 256 + threadIdx.x) << 3;
  float4 f0 = *(const float4*)(in + i);
  float4 f1 = *(const float4*)(in + i + 4);
  short8 o;
  o[0] = (short)f2b(f0.x); o[1] = (short)f2b(f0.y); o[2] = (short)f2b(f0.z); o[3] = (short)f2b(f0.w);
  o[4] = (short)f2b(f1.x); o[5] = (short)f2b(f1.y); o[6] = (short)f2b(f1.z); o[7] = (short)f2b(f1.w);
  *(short8*)(out + i) = o;
}

// ---------------- W [K=1024][N=1024] f32 -> Wt [N][K] bf16 ----------------
__global__ void transp_w_kernel(const float* __restrict__ W, unsigned short* __restrict__ Wt) {
  __shared__ float tile[32][33];
  int tx = threadIdx.x, ty = threadIdx.y;
  int n0 = blockIdx.x * 32, k0 = blockIdx.y * 32;
#pragma unroll
  for (int j = 0; j < 4; ++j)
    tile[ty + j * 8][tx] = W[(k0 + ty + j * 8) * 1024 + n0 + tx];
  __syncthreads();
#pragma unroll
  for (int j = 0; j < 4; ++j)
    Wt[(n0 + ty + j * 8) * 1024 + k0 + tx] = f2b(tile[tx][ty + j * 8]);
}

// ---------------- GEMM: C[M=4096, N] = A[4096,1024]bf16 * Bt[N,1024]bf16 ----------------
// MODE 0: N=3072 fused QKV. n<1024 -> qb, n<2048 -> kb, else vt transposed [bh][dh][S].
// MODE 1: N=1024, f32 output to d_out.
template <int MODE>
__global__ __launch_bounds__(256, 2)
void gemm_kernel(const unsigned short* __restrict__ A,
                 const unsigned short* __restrict__ Bt,
                 unsigned short* __restrict__ q_out,
                 unsigned short* __restrict__ k_out,
                 unsigned short* __restrict__ v_out,
                 float* __restrict__ f_out) {
  const int K = 1024;
  __shared__ __align__(16) unsigned short As[128 * 32];
  __shared__ __align__(16) unsigned short Bs[128 * 32];
  int tid = threadIdx.x;
  int wave = tid >> 6, lane = tid & 63;
  int wm = wave >> 1, wn = wave & 1;
  int l15 = lane & 15, lg = lane >> 4;
  int m0 = blockIdx.y * 128, n0 = blockIdx.x * 128;

  f32x4 acc[4][4] = {};

  // staging: each wave issues 2 chunks (1KB each) for A and B.
  int chRow = lane >> 2;            // 0..15
  int chCol = (lane & 3) << 3;      // 0,8,16,24 elems
  const unsigned short* gA0 = A  + (m0 + (wave << 5) + chRow) * K + chCol;
  const unsigned short* gA1 = gA0 + 16 * K;
  const unsigned short* gB0 = Bt + (n0 + (wave << 5) + chRow) * K + chCol;
  const unsigned short* gB1 = gB0 + 16 * K;
  unsigned short* lA0 = As + (wave * 2 + 0) * 512;
  unsigned short* lA1 = As + (wave * 2 + 1) * 512;
  unsigned short* lB0 = Bs + (wave * 2 + 0) * 512;
  unsigned short* lB1 = Bs + (wave * 2 + 1) * 512;

  const unsigned short* pa = As + (wm * 64 + l15) * 32 + (lg << 3);
  const unsigned short* pb = Bs + (wn * 64 + l15) * 32 + (lg << 3);

  for (int kt = 0; kt < 32; ++kt) {
    __syncthreads();
    gload_lds16(gA0, lA0); gload_lds16(gA1, lA1);
    gload_lds16(gB0, lB0); gload_lds16(gB1, lB1);
    gA0 += 32; gA1 += 32; gB0 += 32; gB1 += 32;
    __syncthreads();
    short8 a[4], b[4];
#pragma unroll
    for (int mt = 0; mt < 4; ++mt) a[mt] = *(const short8*)(pa + mt * 16 * 32);
#pragma unroll
    for (int nt = 0; nt < 4; ++nt) b[nt] = *(const short8*)(pb + nt * 16 * 32);
#pragma unroll
    for (int mt = 0; mt < 4; ++mt)
#pragma unroll
      for (int nt = 0; nt < 4; ++nt)
        acc[mt][nt] = mfma16(a[mt], b[nt], acc[mt][nt]);
  }

  // epilogue: C row = m0+wm*64+mt*16+lg*4+r, col = n0+wn*64+nt*16+l15
#pragma unroll
  for (int mt = 0; mt < 4; ++mt) {
#pragma unroll
    for (int nt = 0; nt < 4; ++nt) {
      int m = m0 + wm * 64 + mt * 16 + (lg << 2);
      int n = n0 + wn * 64 + nt * 16 + l15;
      if (MODE == 1) {
#pragma unroll
        for (int r = 0; r < 4; ++r)
          f_out[(m + r) * 1024 + n] = acc[mt][nt][r];
      } else {
        int w = n >> 10, nn = n & 1023;
        if (w == 0) {
#pragma unroll
          for (int r = 0; r < 4; ++r)
            q_out[(m + r) * 1024 + nn] = f2b(acc[mt][nt][r]);
        } else if (w == 1) {
#pragma unroll
          for (int r = 0; r < 4; ++r)
            k_out[(m + r) * 1024 + nn] = f2b(acc[mt][nt][r]);
        } else {
          int h = nn >> 6, dh = nn & 63;
          int b = m >> 11, s = m & 2047;
          short4v pk;
#pragma unroll
          for (int r = 0; r < 4; ++r) pk[r] = (short)f2b(acc[mt][nt][r]);
          *(short4v*)(v_out + ((b * 16 + h) * 64 + dh) * 2048 + s) = pk;
        }
      }
    }
  }
}

// ---------------- flash attention ----------------
// grid: 1024 blocks = (bh 0..31) x (qtile 0..31); 4 waves/block, 16 q-rows/wave.
// qb,kb: [4096][1024] bf16 (head cols h*64..); vt: [bh][64][2048]; ob: [bh][2048][64].
__global__ __launch_bounds__(256, 2)
void attn_kernel(const unsigned short* __restrict__ qb,
                 const unsigned short* __restrict__ kb,
                 const unsigned short* __restrict__ vt,
                 unsigned short* __restrict__ ob) {
  __shared__ __align__(16) unsigned short plds[4][16][72];  // +8 pad: 144B rows, 2-way banks
  int tid = threadIdx.x, wave = tid >> 6, lane = tid & 63;
  int l15 = lane & 15, lg = lane >> 4;
  int bid = blockIdx.x;
  int qt = bid & 31, bh = bid >> 5;
  int b = bh >> 4, h = bh & 15;
  int q0 = qt * 64 + wave * 16;

  // Q fragments (held for whole kernel)
  const unsigned short* qptr = qb + (b * 2048 + q0 + l15) * 1024 + h * 64 + (lg << 3);
  short8 aq0 = *(const short8*)(qptr);
  short8 aq1 = *(const short8*)(qptr + 32);

  f32x4 oacc[4] = {};
  float mrun[4], lrun[4];
#pragma unroll
  for (int r = 0; r < 4; ++r) { mrun[r] = -1e30f; lrun[r] = 0.f; }

  const unsigned short* kbase = kb + (b * 2048) * 1024 + h * 64 + (lg << 3);
  const unsigned short* vbase = vt + (bh * 64) * 2048 + (lg << 3);

  for (int t = 0; t < 32; ++t) {
    int kv0 = t * 64;
    // QK^T: 16x64 scores per wave
    f32x4 s[4];
#pragma unroll
    for (int nt = 0; nt < 4; ++nt) {
      const unsigned short* kp = kbase + (kv0 + nt * 16 + l15) * 1024;
      short8 bk0 = *(const short8*)kp;
      short8 bk1 = *(const short8*)(kp + 32);
      f32x4 z = {};
      z = mfma16(aq0, bk0, z);
      z = mfma16(aq1, bk1, z);
      s[nt] = z;
    }
    // online softmax per row r (rows replicated over 16-lane groups)
#pragma unroll
    for (int r = 0; r < 4; ++r) {
      float mx = fmaxf(fmaxf(s[0][r], s[1][r]), fmaxf(s[2][r], s[3][r]));
      mx = fmaxf(mx, __shfl_xor(mx, 1));
      mx = fmaxf(mx, __shfl_xor(mx, 2));
      mx = fmaxf(mx, __shfl_xor(mx, 4));
      mx = fmaxf(mx, __shfl_xor(mx, 8));
      float mn = fmaxf(mrun[r], mx);
      float corr = __expf(mrun[r] - mn);
      mrun[r] = mn;
      float ps = 0.f;
#pragma unroll
      for (int nt = 0; nt < 4; ++nt) {
        float p = __expf(s[nt][r] - mn);
        s[nt][r] = p;
        ps += p;
      }
      ps += __shfl_xor(ps, 1);
      ps += __shfl_xor(ps, 2);
      ps += __shfl_xor(ps, 4);
      ps += __shfl_xor(ps, 8);
      lrun[r] = lrun[r] * corr + ps;
#pragma unroll
      for (int nt = 0; nt < 4; ++nt) oacc[nt][r] *= corr;
    }
    // P -> LDS (C-layout write), read back in A-layout
#pragma unroll
    for (int nt = 0; nt < 4; ++nt)
#pragma unroll
      for (int r = 0; r < 4; ++r)
        plds[wave][(lg << 2) + r][nt * 16 + l15] = f2b(s[nt][r]);
    short8 pa0 = *(const short8*)&plds[wave][l15][(lg << 3)];
    short8 pa1 = *(const short8*)&plds[wave][l15][32 + (lg << 3)];
    // PV: P(16x64) * V(64x64), V from vt [dh][S]
#pragma unroll
    for (int nt = 0; nt < 4; ++nt) {
      const unsigned short* vp = vbase + (nt * 16 + l15) * 2048 + kv0;
      short8 bv0 = *(const short8*)vp;
      short8 bv1 = *(const short8*)(vp + 32);
      oacc[nt] = mfma16(pa0, bv0, oacc[nt]);
      oacc[nt] = mfma16(pa1, bv1, oacc[nt]);
    }
  }

  // finalize: divide by lsum, write [bh][s][dh] order (reshape quirk)
  float inv[4];
#pragma unroll
  for (int r = 0; r < 4; ++r) inv[r] = 1.f / lrun[r];
#pragma unroll
  for (int nt = 0; nt < 4; ++nt)
#pragma unroll
    for (int r = 0; r < 4; ++r)
      ob[(bh * 2048 + q0 + (lg << 2) + r) * 64 + nt * 16 + l15] = f2b(oacc[nt][r] * inv[r]);
}

extern "C" void kernel_launch(void* const* d_in, const int* in_sizes, int n_in,
                              void* d_out, int out_size, void* d_ws, size_t ws_size,
                              hipStream_t stream) {
  (void)in_sizes; (void)n_in; (void)out_size; (void)ws_size;
  const float* x  = (const float*)d_in[0];
  const float* Wq = (const float*)d_in[1];
  const float* Wk = (const float*)d_in[2];
  const float* Wv = (const float*)d_in[3];
  const float* Wo = (const float*)d_in[4];
  float* out = (float*)d_out;

  unsigned short* ws = (unsigned short*)d_ws;
  const int MB4 = 4 * 1024 * 1024;  // 4M elements = 8MB
  unsigned short* xb = ws;
  unsigned short* wt = xb + MB4;    // [3072+1024][1024]: Wq^T,Wk^T,Wv^T,Wo^T
  unsigned short* qb = wt + MB4;
  unsigned short* kb = qb + MB4;
  unsigned short* vt = kb + MB4;
  unsigned short* cb = vt + MB4;

  cvt_x_kernel<<<2048, 256, 0, stream>>>(x, xb);
  transp_w_kernel<<<dim3(32, 32), dim3(32, 8), 0, stream>>>(Wq, wt);
  transp_w_kernel<<<dim3(32, 32), dim3(32, 8), 0, stream>>>(Wk, wt + 1 * 1024 * 1024);
  transp_w_kernel<<<dim3(32, 32), dim3(32, 8), 0, stream>>>(Wv, wt + 2 * 1024 * 1024);
  transp_w_kernel<<<dim3(32, 32), dim3(32, 8), 0, stream>>>(Wo, wt + 3 * 1024 * 1024);

  gemm_kernel<0><<<dim3(24, 32), 256, 0, stream>>>(xb, wt, qb, kb, vt, nullptr);
  attn_kernel<<<1024, 256, 0, stream>>>(qb, kb, vt, cb);
  gemm_kernel<1><<<dim3(8, 32), 256, 0, stream>>>(cb, wt + 3 * 1024 * 1024,
                                                  nullptr, nullptr, nullptr, out);
}

// Round 2
// 366.832 us; speedup vs baseline: 1.0242x; 1.0242x over previous
//
#include <hip/hip_runtime.h>
#include <hip/hip_bf16.h>

// B=2, S=2048, D=1024, H=16, dh=64.  All compute bf16 MFMA, fp32 accum/softmax.
// ws layout (unsigned short elems): xb[4M] wt[4M] qb[4M] kb[4M] vt[4M] cb[4M] = 48MB.

typedef short short8  __attribute__((ext_vector_type(8)));
typedef short short4v __attribute__((ext_vector_type(4)));
typedef float f32x4   __attribute__((ext_vector_type(4)));

#define GLOB_AS __attribute__((address_space(1)))
#define LDS_AS  __attribute__((address_space(3)))

__device__ __forceinline__ unsigned short f2b(float f) {
  union { float f; unsigned u; } v; v.f = f;
  return (unsigned short)((v.u + 0x7fffu + ((v.u >> 16) & 1u)) >> 16);
}

__device__ __forceinline__ float b2f(unsigned short u) {
  union { unsigned u; float f; } v; v.u = (unsigned)u << 16;
  return v.f;
}

#if __has_builtin(__builtin_amdgcn_exp2f)
__device__ __forceinline__ float exp2_hw(float x) { return __builtin_amdgcn_exp2f(x); }
#else
__device__ __forceinline__ float exp2_hw(float x) {
  float r; asm("v_exp_f32 %0, %1" : "=v"(r) : "v"(x)); return r;
}
#endif

__device__ __forceinline__ f32x4 mfma16(short8 a, short8 b, f32x4 c) {
  return __builtin_amdgcn_mfma_f32_16x16x32_bf16(a, b, c, 0, 0, 0);
}

__device__ __forceinline__ void gload_lds16(const unsigned short* g, unsigned short* l) {
  __builtin_amdgcn_global_load_lds((const GLOB_AS void*)g, (LDS_AS void*)l, 16, 0, 0);
}

// ---------------- f32 -> bf16 elementwise (x) ----------------
__global__ void cvt_x_kernel(const float* __restrict__ in, unsigned short* __restrict__ out) {
  int i = (blockIdx.x * 256 + threadIdx.x) << 3;
  float4 f0 = *(const float4*)(in + i);
  float4 f1 = *(const float4*)(in + i + 4);
  short8 o;
  o[0] = (short)f2b(f0.x); o[1] = (short)f2b(f0.y); o[2] = (short)f2b(f0.z); o[3] = (short)f2b(f0.w);
  o[4] = (short)f2b(f1.x); o[5] = (short)f2b(f1.y); o[6] = (short)f2b(f1.z); o[7] = (short)f2b(f1.w);
  *(short8*)(out + i) = o;
}

// ---------------- 4x W [K=1024][N=1024] f32 -> Wt [N][K] bf16, fused ----------------
__global__ void transp_w4_kernel(const float* __restrict__ W0, const float* __restrict__ W1,
                                 const float* __restrict__ W2, const float* __restrict__ W3,
                                 unsigned short* __restrict__ Wt) {
  __shared__ float tile[32][33];
  int z = blockIdx.z;
  const float* W = (z == 0) ? W0 : (z == 1) ? W1 : (z == 2) ? W2 : W3;
  unsigned short* dst = Wt + z * 1024 * 1024;
  int tx = threadIdx.x, ty = threadIdx.y;
  int n0 = blockIdx.x * 32, k0 = blockIdx.y * 32;
#pragma unroll
  for (int j = 0; j < 4; ++j)
    tile[ty + j * 8][tx] = W[(k0 + ty + j * 8) * 1024 + n0 + tx];
  __syncthreads();
#pragma unroll
  for (int j = 0; j < 4; ++j)
    dst[(n0 + ty + j * 8) * 1024 + k0 + tx] = f2b(tile[tx][ty + j * 8]);
}

// ---------------- GEMM: C[M=4096, N] = A[4096,1024]bf16 * Bt[N,1024]bf16 ----------------
// MODE 0: N=3072 fused QKV. n<1024 -> qb, n<2048 -> kb, else vt transposed [bh][dh][S].
// MODE 1: N=1024, f32 output to d_out.
template <int MODE>
__global__ __launch_bounds__(256, 2)
void gemm_kernel(const unsigned short* __restrict__ A,
                 const unsigned short* __restrict__ Bt,
                 unsigned short* __restrict__ q_out,
                 unsigned short* __restrict__ k_out,
                 unsigned short* __restrict__ v_out,
                 float* __restrict__ f_out) {
  const int K = 1024;
  const int NBX = (MODE == 0) ? 24 : 8;
  __shared__ __align__(16) unsigned short As[128 * 32];
  __shared__ __align__(16) unsigned short Bs[128 * 32];
  int tid = threadIdx.x;
  int wave = tid >> 6, lane = tid & 63;
  int wm = wave >> 1, wn = wave & 1;
  int l15 = lane & 15, lg = lane >> 4;

  // bijective XCD swizzle (nwg = NBX*32, both 768 and 256 are %8==0)
  int bid0 = blockIdx.y * NBX + blockIdx.x;
  int cpx = (NBX * 32) >> 3;
  int swz = (bid0 & 7) * cpx + (bid0 >> 3);
  int m0 = (swz / NBX) * 128, n0 = (swz % NBX) * 128;

  f32x4 acc[4][4] = {};

  // staging: each wave issues 2 chunks (1KB each) for A and B.
  int chRow = lane >> 2;            // 0..15
  int chCol = (lane & 3) << 3;      // 0,8,16,24 elems
  const unsigned short* gA0 = A  + (m0 + (wave << 5) + chRow) * K + chCol;
  const unsigned short* gA1 = gA0 + 16 * K;
  const unsigned short* gB0 = Bt + (n0 + (wave << 5) + chRow) * K + chCol;
  const unsigned short* gB1 = gB0 + 16 * K;
  unsigned short* lA0 = As + (wave * 2 + 0) * 512;
  unsigned short* lA1 = As + (wave * 2 + 1) * 512;
  unsigned short* lB0 = Bs + (wave * 2 + 0) * 512;
  unsigned short* lB1 = Bs + (wave * 2 + 1) * 512;

  const unsigned short* pa = As + (wm * 64 + l15) * 32 + (lg << 3);
  const unsigned short* pb = Bs + (wn * 64 + l15) * 32 + (lg << 3);

  for (int kt = 0; kt < 32; ++kt) {
    __syncthreads();
    gload_lds16(gA0, lA0); gload_lds16(gA1, lA1);
    gload_lds16(gB0, lB0); gload_lds16(gB1, lB1);
    gA0 += 32; gA1 += 32; gB0 += 32; gB1 += 32;
    __syncthreads();
    short8 a[4], b[4];
#pragma unroll
    for (int mt = 0; mt < 4; ++mt) a[mt] = *(const short8*)(pa + mt * 16 * 32);
#pragma unroll
    for (int nt = 0; nt < 4; ++nt) b[nt] = *(const short8*)(pb + nt * 16 * 32);
#pragma unroll
    for (int mt = 0; mt < 4; ++mt)
#pragma unroll
      for (int nt = 0; nt < 4; ++nt)
        acc[mt][nt] = mfma16(a[mt], b[nt], acc[mt][nt]);
  }

  // epilogue: C row = m0+wm*64+mt*16+lg*4+r, col = n0+wn*64+nt*16+l15
#pragma unroll
  for (int mt = 0; mt < 4; ++mt) {
#pragma unroll
    for (int nt = 0; nt < 4; ++nt) {
      int m = m0 + wm * 64 + mt * 16 + (lg << 2);
      int n = n0 + wn * 64 + nt * 16 + l15;
      if (MODE == 1) {
#pragma unroll
        for (int r = 0; r < 4; ++r)
          f_out[(m + r) * 1024 + n] = acc[mt][nt][r];
      } else {
        int w = n >> 10, nn = n & 1023;
        if (w == 0) {
#pragma unroll
          for (int r = 0; r < 4; ++r)
            q_out[(m + r) * 1024 + nn] = f2b(acc[mt][nt][r]);
        } else if (w == 1) {
#pragma unroll
          for (int r = 0; r < 4; ++r)
            k_out[(m + r) * 1024 + nn] = f2b(acc[mt][nt][r]);
        } else {
          int h = nn >> 6, dh = nn & 63;
          int b = m >> 11, s = m & 2047;
          short4v pk;
#pragma unroll
          for (int r = 0; r < 4; ++r) pk[r] = (short)f2b(acc[mt][nt][r]);
          *(short4v*)(v_out + ((b * 16 + h) * 64 + dh) * 2048 + s) = pk;
        }
      }
    }
  }
}

// ---------------- flash attention (no-max softmax: scores bounded ~±50, e^s fits f32) ----
// grid: 2048 blocks = bh(32) x qtile(64); 2 waves/block, 16 q-rows/wave.
// qb,kb: [4096][1024] bf16 (head cols h*64..); vt: [bh][64][2048]; ob: [bh][2048][64].
__global__ __launch_bounds__(128, 4)
void attn_kernel(const unsigned short* __restrict__ qb,
                 const unsigned short* __restrict__ kb,
                 const unsigned short* __restrict__ vt,
                 unsigned short* __restrict__ ob) {
  __shared__ __align__(16) unsigned short plds[2][2][16][72];  // [wave][buf][row][col+pad]
  int tid = threadIdx.x, wave = tid >> 6, lane = tid & 63;
  int l15 = lane & 15, lg = lane >> 4;
  int bid = blockIdx.x;
  int qt = bid & 63, bh = bid >> 6;
  int b = bh >> 4, h = bh & 15;
  int q0 = qt * 32 + wave * 16;

  // Q fragments (held for whole kernel)
  const unsigned short* qptr = qb + (b * 2048 + q0 + l15) * 1024 + h * 64 + (lg << 3);
  short8 aq0 = *(const short8*)(qptr);
  short8 aq1 = *(const short8*)(qptr + 32);

  f32x4 oacc[4] = {};
  float lrun[4] = {0.f, 0.f, 0.f, 0.f};  // per-lane partial sums of rounded P

  const unsigned short* kbase = kb + (b * 2048) * 1024 + h * 64 + (lg << 3);
  const unsigned short* vbase = vt + (bh * 64) * 2048 + (lg << 3);
  const float LOG2E = 1.4426950408889634f;

#pragma unroll 2
  for (int t = 0; t < 32; ++t) {
    int kv0 = t * 64;
    int buf = t & 1;
    // QK^T: 16x64 scores per wave
    f32x4 s[4];
#pragma unroll
    for (int nt = 0; nt < 4; ++nt) {
      const unsigned short* kp = kbase + (kv0 + nt * 16 + l15) * 1024;
      short8 bk0 = *(const short8*)kp;
      short8 bk1 = *(const short8*)(kp + 32);
      f32x4 z = {};
      z = mfma16(aq0, bk0, z);
      z = mfma16(aq1, bk1, z);
      s[nt] = z;
    }
    // P = e^s (no max subtraction needed; |s| <~ 50), partial-sum the ROUNDED values
#pragma unroll
    for (int nt = 0; nt < 4; ++nt)
#pragma unroll
      for (int r = 0; r < 4; ++r) {
        float p = exp2_hw(s[nt][r] * LOG2E);
        unsigned short pb = f2b(p);
        plds[wave][buf][(lg << 2) + r][nt * 16 + l15] = pb;
        lrun[r] += b2f(pb);
      }
    short8 pa0 = *(const short8*)&plds[wave][buf][l15][(lg << 3)];
    short8 pa1 = *(const short8*)&plds[wave][buf][l15][32 + (lg << 3)];
    // PV: P(16x64) * V(64x64), V from vt [dh][S]
#pragma unroll
    for (int nt = 0; nt < 4; ++nt) {
      const unsigned short* vp = vbase + (nt * 16 + l15) * 2048 + kv0;
      short8 bv0 = *(const short8*)vp;
      short8 bv1 = *(const short8*)(vp + 32);
      oacc[nt] = mfma16(pa0, bv0, oacc[nt]);
      oacc[nt] = mfma16(pa1, bv1, oacc[nt]);
    }
  }

  // single end-of-kernel row-sum reduce (rows live within a 16-lane group)
  float inv[4];
#pragma unroll
  for (int r = 0; r < 4; ++r) {
    float ssum = lrun[r];
    ssum += __shfl_xor(ssum, 1);
    ssum += __shfl_xor(ssum, 2);
    ssum += __shfl_xor(ssum, 4);
    ssum += __shfl_xor(ssum, 8);
    inv[r] = 1.f / ssum;
  }
#pragma unroll
  for (int nt = 0; nt < 4; ++nt)
#pragma unroll
    for (int r = 0; r < 4; ++r)
      ob[(bh * 2048 + q0 + (lg << 2) + r) * 64 + nt * 16 + l15] = f2b(oacc[nt][r] * inv[r]);
}

extern "C" void kernel_launch(void* const* d_in, const int* in_sizes, int n_in,
                              void* d_out, int out_size, void* d_ws, size_t ws_size,
                              hipStream_t stream) {
  (void)in_sizes; (void)n_in; (void)out_size; (void)ws_size;
  const float* x  = (const float*)d_in[0];
  const float* Wq = (const float*)d_in[1];
  const float* Wk = (const float*)d_in[2];
  const float* Wv = (const float*)d_in[3];
  const float* Wo = (const float*)d_in[4];
  float* out = (float*)d_out;

  unsigned short* ws = (unsigned short*)d_ws;
  const int MB4 = 4 * 1024 * 1024;  // 4M elements = 8MB
  unsigned short* xb = ws;
  unsigned short* wt = xb + MB4;    // [3072+1024][1024]: Wq^T,Wk^T,Wv^T,Wo^T
  unsigned short* qb = wt + MB4;
  unsigned short* kb = qb + MB4;
  unsigned short* vt = kb + MB4;
  unsigned short* cb = vt + MB4;

  cvt_x_kernel<<<2048, 256, 0, stream>>>(x, xb);
  transp_w4_kernel<<<dim3(32, 32, 4), dim3(32, 8), 0, stream>>>(Wq, Wk, Wv, Wo, wt);

  gemm_kernel<0><<<dim3(24, 32), 256, 0, stream>>>(xb, wt, qb, kb, vt, nullptr);
  attn_kernel<<<2048, 128, 0, stream>>>(qb, kb, vt, cb);
  gemm_kernel<1><<<dim3(8, 32), 256, 0, stream>>>(cb, wt + 3 * 1024 * 1024,
                                                  nullptr, nullptr, nullptr, out);
}

// Round 3
// 204.566 us; speedup vs baseline: 1.8366x; 1.7932x over previous
//
#include <hip/hip_runtime.h>
#include <hip/hip_bf16.h>

// B=2, S=2048, D=1024, H=16, dh=64.  All compute bf16 MFMA, fp32 accum/softmax.
// ws layout (unsigned short elems): xb[4M] wt[4M] qb[4M] kb[4M] vt[4M] cb[4M] = 48MB.

typedef short short8  __attribute__((ext_vector_type(8)));
typedef short short4v __attribute__((ext_vector_type(4)));
typedef float f32x4   __attribute__((ext_vector_type(4)));

#define GLOB_AS __attribute__((address_space(1)))
#define LDS_AS  __attribute__((address_space(3)))

__device__ __forceinline__ unsigned short f2b(float f) {
  union { float f; unsigned u; } v; v.f = f;
  return (unsigned short)((v.u + 0x7fffu + ((v.u >> 16) & 1u)) >> 16);
}

__device__ __forceinline__ float b2f(unsigned short u) {
  union { unsigned u; float f; } v; v.u = (unsigned)u << 16;
  return v.f;
}

__device__ __forceinline__ float exp2_hw(float x) {
  float r; asm("v_exp_f32 %0, %1" : "=v"(r) : "v"(x)); return r;
}

__device__ __forceinline__ f32x4 mfma16(short8 a, short8 b, f32x4 c) {
  return __builtin_amdgcn_mfma_f32_16x16x32_bf16(a, b, c, 0, 0, 0);
}

__device__ __forceinline__ void gload_lds16(const unsigned short* g, unsigned short* l) {
  __builtin_amdgcn_global_load_lds((const GLOB_AS void*)g, (LDS_AS void*)l, 16, 0, 0);
}

// ---------------- f32 -> bf16 elementwise (x) ----------------
__global__ void cvt_x_kernel(const float* __restrict__ in, unsigned short* __restrict__ out) {
  int i = (blockIdx.x * 256 + threadIdx.x) << 3;
  float4 f0 = *(const float4*)(in + i);
  float4 f1 = *(const float4*)(in + i + 4);
  short8 o;
  o[0] = (short)f2b(f0.x); o[1] = (short)f2b(f0.y); o[2] = (short)f2b(f0.z); o[3] = (short)f2b(f0.w);
  o[4] = (short)f2b(f1.x); o[5] = (short)f2b(f1.y); o[6] = (short)f2b(f1.z); o[7] = (short)f2b(f1.w);
  *(short8*)(out + i) = o;
}

// ---------------- 4x W [K=1024][N=1024] f32 -> Wt [N][K] bf16, fused ----------------
__global__ void transp_w4_kernel(const float* __restrict__ W0, const float* __restrict__ W1,
                                 const float* __restrict__ W2, const float* __restrict__ W3,
                                 unsigned short* __restrict__ Wt) {
  __shared__ float tile[32][33];
  int z = blockIdx.z;
  const float* W = (z == 0) ? W0 : (z == 1) ? W1 : (z == 2) ? W2 : W3;
  unsigned short* dst = Wt + z * 1024 * 1024;
  int tx = threadIdx.x, ty = threadIdx.y;
  int n0 = blockIdx.x * 32, k0 = blockIdx.y * 32;
#pragma unroll
  for (int j = 0; j < 4; ++j)
    tile[ty + j * 8][tx] = W[(k0 + ty + j * 8) * 1024 + n0 + tx];
  __syncthreads();
#pragma unroll
  for (int j = 0; j < 4; ++j)
    dst[(n0 + ty + j * 8) * 1024 + k0 + tx] = f2b(tile[tx][ty + j * 8]);
}

// ---------------- GEMM: C[M=4096, N] = A[4096,1024]bf16 * Bt[N,1024]bf16 ----------------
template <int MODE>
__global__ __launch_bounds__(256, 2)
void gemm_kernel(const unsigned short* __restrict__ A,
                 const unsigned short* __restrict__ Bt,
                 unsigned short* __restrict__ q_out,
                 unsigned short* __restrict__ k_out,
                 unsigned short* __restrict__ v_out,
                 float* __restrict__ f_out) {
  const int K = 1024;
  const int NBX = (MODE == 0) ? 24 : 8;
  __shared__ __align__(16) unsigned short As[128 * 32];
  __shared__ __align__(16) unsigned short Bs[128 * 32];
  int tid = threadIdx.x;
  int wave = tid >> 6, lane = tid & 63;
  int wm = wave >> 1, wn = wave & 1;
  int l15 = lane & 15, lg = lane >> 4;

  int bid0 = blockIdx.y * NBX + blockIdx.x;
  int cpx = (NBX * 32) >> 3;
  int swz = (bid0 & 7) * cpx + (bid0 >> 3);
  int m0 = (swz / NBX) * 128, n0 = (swz % NBX) * 128;

  f32x4 acc[4][4] = {};

  int chRow = lane >> 2;
  int chCol = (lane & 3) << 3;
  const unsigned short* gA0 = A  + (m0 + (wave << 5) + chRow) * K + chCol;
  const unsigned short* gA1 = gA0 + 16 * K;
  const unsigned short* gB0 = Bt + (n0 + (wave << 5) + chRow) * K + chCol;
  const unsigned short* gB1 = gB0 + 16 * K;
  unsigned short* lA0 = As + (wave * 2 + 0) * 512;
  unsigned short* lA1 = As + (wave * 2 + 1) * 512;
  unsigned short* lB0 = Bs + (wave * 2 + 0) * 512;
  unsigned short* lB1 = Bs + (wave * 2 + 1) * 512;

  const unsigned short* pa = As + (wm * 64 + l15) * 32 + (lg << 3);
  const unsigned short* pb = Bs + (wn * 64 + l15) * 32 + (lg << 3);

  for (int kt = 0; kt < 32; ++kt) {
    __syncthreads();
    gload_lds16(gA0, lA0); gload_lds16(gA1, lA1);
    gload_lds16(gB0, lB0); gload_lds16(gB1, lB1);
    gA0 += 32; gA1 += 32; gB0 += 32; gB1 += 32;
    __syncthreads();
    short8 a[4], b[4];
#pragma unroll
    for (int mt = 0; mt < 4; ++mt) a[mt] = *(const short8*)(pa + mt * 16 * 32);
#pragma unroll
    for (int nt = 0; nt < 4; ++nt) b[nt] = *(const short8*)(pb + nt * 16 * 32);
#pragma unroll
    for (int mt = 0; mt < 4; ++mt)
#pragma unroll
      for (int nt = 0; nt < 4; ++nt)
        acc[mt][nt] = mfma16(a[mt], b[nt], acc[mt][nt]);
  }

#pragma unroll
  for (int mt = 0; mt < 4; ++mt) {
#pragma unroll
    for (int nt = 0; nt < 4; ++nt) {
      int m = m0 + wm * 64 + mt * 16 + (lg << 2);
      int n = n0 + wn * 64 + nt * 16 + l15;
      if (MODE == 1) {
#pragma unroll
        for (int r = 0; r < 4; ++r)
          f_out[(m + r) * 1024 + n] = acc[mt][nt][r];
      } else {
        int w = n >> 10, nn = n & 1023;
        if (w == 0) {
#pragma unroll
          for (int r = 0; r < 4; ++r)
            q_out[(m + r) * 1024 + nn] = f2b(acc[mt][nt][r]);
        } else if (w == 1) {
#pragma unroll
          for (int r = 0; r < 4; ++r)
            k_out[(m + r) * 1024 + nn] = f2b(acc[mt][nt][r]);
        } else {
          int h = nn >> 6, dh = nn & 63;
          int b = m >> 11, s = m & 2047;
          short4v pk;
#pragma unroll
          for (int r = 0; r < 4; ++r) pk[r] = (short)f2b(acc[mt][nt][r]);
          *(short4v*)(v_out + ((b * 16 + h) * 64 + dh) * 2048 + s) = pk;
        }
      }
    }
  }
}

// ---------------- flash attention, LDS-staged K/V, 2-phase pipeline ----------------
// grid: 512 blocks = bh(32) x qtile(16); 4 waves/block, 32 q-rows/wave (m=2 frags).
// K tile [64 kv][64 dh], V tile [64 dh][64 kv] staged in LDS, XOR-chunk-swizzled.
// No-max softmax (scores bounded ~+-50, e^s fits f32); row-sum deferred to epilogue.
__global__ __launch_bounds__(256, 2)
void attn_kernel(const unsigned short* __restrict__ qb,
                 const unsigned short* __restrict__ kb,
                 const unsigned short* __restrict__ vt,
                 unsigned short* __restrict__ ob) {
  __shared__ __align__(16) unsigned short Ks[2][4096];
  __shared__ __align__(16) unsigned short Vs[2][4096];
  __shared__ __align__(16) unsigned short plds[4][2][16][72];
  int tid = threadIdx.x, wave = tid >> 6, lane = tid & 63;
  int l15 = lane & 15, lg = lane >> 4;

  // XCD swizzle: 512 blocks, XCD x gets work_ids x*64..x*64+63 = 4 whole bh's
  int bid = blockIdx.x;
  int wid = (bid & 7) * 64 + (bid >> 3);
  int bh = wid >> 4, qt = wid & 15;
  int b = bh >> 4, h = bh & 15;
  int q0 = qt * 128 + wave * 32;

  // Q fragments (held in registers for whole kernel)
  short8 aq[2][2];
#pragma unroll
  for (int m = 0; m < 2; ++m)
#pragma unroll
    for (int kt = 0; kt < 2; ++kt)
      aq[m][kt] = *(const short8*)(qb + (b * 2048 + q0 + m * 16 + l15) * 1024 +
                                   h * 64 + kt * 32 + (lg << 3));

  // staging source addresses: seg = wave*2+j covers rows seg*8 + (lane>>3);
  // chunk placed at LDS slot (lane&7) comes from global chunk (lane&7)^(lane>>3).
  int srow = lane >> 3;
  int csrc = ((lane & 7) ^ srow) << 3;
  const unsigned short* gK0 = kb + (b * 2048 + wave * 16 + srow) * 1024 + h * 64 + csrc;
  const unsigned short* gK1 = gK0 + 8 * 1024;
  const unsigned short* gV0 = vt + (bh * 64 + wave * 16 + srow) * 2048 + csrc;
  const unsigned short* gV1 = gV0 + 8 * 2048;
  unsigned short* lK0[2], *lK1[2], *lV0[2], *lV1[2];
#pragma unroll
  for (int u = 0; u < 2; ++u) {
    lK0[u] = &Ks[u][(wave * 2 + 0) * 512]; lK1[u] = &Ks[u][(wave * 2 + 1) * 512];
    lV0[u] = &Vs[u][(wave * 2 + 0) * 512]; lV1[u] = &Vs[u][(wave * 2 + 1) * 512];
  }

  // prologue: stage tile 0 into buf 0
  gload_lds16(gK0, lK0[0]); gload_lds16(gK1, lK1[0]);
  gload_lds16(gV0, lV0[0]); gload_lds16(gV1, lV1[0]);
  gK0 += 65536; gK1 += 65536; gV0 += 64; gV1 += 64;

  f32x4 oacc[2][4] = {};
  float lrun[2][4] = {};
  const float LOG2E = 1.4426950408889634f;

  for (int t = 0; t < 32; ++t) {
    int buf = t & 1;
    __syncthreads();  // drains vmcnt -> tile t staged; also fences prev-iter LDS reads
    if (t < 31) {
      gload_lds16(gK0, lK0[buf ^ 1]); gload_lds16(gK1, lK1[buf ^ 1]);
      gload_lds16(gV0, lV0[buf ^ 1]); gload_lds16(gV1, lV1[buf ^ 1]);
      gK0 += 65536; gK1 += 65536; gV0 += 64; gV1 += 64;
    }

    const unsigned short* Kb = &Ks[buf][0];
    const unsigned short* Vb = &Vs[buf][0];

    // QK^T: S[m][nt], kv rows from swizzled K tile
    f32x4 s[2][4];
#pragma unroll
    for (int nt = 0; nt < 4; ++nt) {
      int row = nt * 16 + l15, x = row & 7;
      short8 bk0 = *(const short8*)(Kb + row * 64 + ((lg ^ x) << 3));
      short8 bk1 = *(const short8*)(Kb + row * 64 + (((4 + lg) ^ x) << 3));
#pragma unroll
      for (int m = 0; m < 2; ++m) {
        f32x4 z = {};
        z = mfma16(aq[m][0], bk0, z);
        z = mfma16(aq[m][1], bk1, z);
        s[m][nt] = z;
      }
    }

    // P = e^s, rounded to bf16; partial row-sums of rounded values
#pragma unroll
    for (int m = 0; m < 2; ++m)
#pragma unroll
      for (int nt = 0; nt < 4; ++nt)
#pragma unroll
        for (int r = 0; r < 4; ++r) {
          float p = exp2_hw(s[m][nt][r] * LOG2E);
          unsigned short pbf = f2b(p);
          plds[wave][m][(lg << 2) + r][nt * 16 + l15] = pbf;
          lrun[m][r] += b2f(pbf);
        }

    // PV: A = P from LDS, B = V^T rows from swizzled V tile
    short8 pa[2][2];
#pragma unroll
    for (int m = 0; m < 2; ++m) {
      pa[m][0] = *(const short8*)&plds[wave][m][l15][(lg << 3)];
      pa[m][1] = *(const short8*)&plds[wave][m][l15][32 + (lg << 3)];
    }
#pragma unroll
    for (int nt = 0; nt < 4; ++nt) {
      int row = nt * 16 + l15, x = row & 7;
      short8 bv0 = *(const short8*)(Vb + row * 64 + ((lg ^ x) << 3));
      short8 bv1 = *(const short8*)(Vb + row * 64 + (((4 + lg) ^ x) << 3));
#pragma unroll
      for (int m = 0; m < 2; ++m) {
        oacc[m][nt] = mfma16(pa[m][0], bv0, oacc[m][nt]);
        oacc[m][nt] = mfma16(pa[m][1], bv1, oacc[m][nt]);
      }
    }
  }

  // epilogue: row-sum reduce across the 16-lane kv groups, normalize, store
#pragma unroll
  for (int m = 0; m < 2; ++m) {
    float inv[4];
#pragma unroll
    for (int r = 0; r < 4; ++r) {
      float ssum = lrun[m][r];
      ssum += __shfl_xor(ssum, 1);
      ssum += __shfl_xor(ssum, 2);
      ssum += __shfl_xor(ssum, 4);
      ssum += __shfl_xor(ssum, 8);
      inv[r] = 1.f / ssum;
    }
#pragma unroll
    for (int nt = 0; nt < 4; ++nt)
#pragma unroll
      for (int r = 0; r < 4; ++r)
        ob[(bh * 2048 + q0 + m * 16 + (lg << 2) + r) * 64 + nt * 16 + l15] =
            f2b(oacc[m][nt][r] * inv[r]);
  }
}

extern "C" void kernel_launch(void* const* d_in, const int* in_sizes, int n_in,
                              void* d_out, int out_size, void* d_ws, size_t ws_size,
                              hipStream_t stream) {
  (void)in_sizes; (void)n_in; (void)out_size; (void)ws_size;
  const float* x  = (const float*)d_in[0];
  const float* Wq = (const float*)d_in[1];
  const float* Wk = (const float*)d_in[2];
  const float* Wv = (const float*)d_in[3];
  const float* Wo = (const float*)d_in[4];
  float* out = (float*)d_out;

  unsigned short* ws = (unsigned short*)d_ws;
  const int MB4 = 4 * 1024 * 1024;
  unsigned short* xb = ws;
  unsigned short* wt = xb + MB4;
  unsigned short* qb = wt + MB4;
  unsigned short* kb = qb + MB4;
  unsigned short* vt = kb + MB4;
  unsigned short* cb = vt + MB4;

  cvt_x_kernel<<<2048, 256, 0, stream>>>(x, xb);
  transp_w4_kernel<<<dim3(32, 32, 4), dim3(32, 8), 0, stream>>>(Wq, Wk, Wv, Wo, wt);

  gemm_kernel<0><<<dim3(24, 32), 256, 0, stream>>>(xb, wt, qb, kb, vt, nullptr);
  attn_kernel<<<512, 256, 0, stream>>>(qb, kb, vt, cb);
  gemm_kernel<1><<<dim3(8, 32), 256, 0, stream>>>(cb, wt + 3 * 1024 * 1024,
                                                  nullptr, nullptr, nullptr, out);
}

// Round 7
// 192.149 us; speedup vs baseline: 1.9553x; 1.0646x over previous
//
#include <hip/hip_runtime.h>
#include <hip/hip_bf16.h>

// B=2, S=2048, D=1024, H=16, dh=64.  All compute bf16 MFMA, fp32 accum/softmax.
// ws layout (unsigned short elems): xb[4M] wt[4M] qb[4M] kb[4M] vt[4M] cb[4M] = 48MB.

typedef short short8  __attribute__((ext_vector_type(8)));
typedef short short4v __attribute__((ext_vector_type(4)));
typedef float f32x4   __attribute__((ext_vector_type(4)));

#define GLOB_AS __attribute__((address_space(1)))
#define LDS_AS  __attribute__((address_space(3)))

__device__ __forceinline__ unsigned short f2b(float f) {
  union { float f; unsigned u; } v; v.f = f;
  return (unsigned short)((v.u + 0x7fffu + ((v.u >> 16) & 1u)) >> 16);
}

__device__ __forceinline__ float b2f(unsigned short u) {
  union { unsigned u; float f; } v; v.u = (unsigned)u << 16;
  return v.f;
}

__device__ __forceinline__ float exp2_hw(float x) {
  float r; asm("v_exp_f32 %0, %1" : "=v"(r) : "v"(x)); return r;
}

__device__ __forceinline__ f32x4 mfma16(short8 a, short8 b, f32x4 c) {
  return __builtin_amdgcn_mfma_f32_16x16x32_bf16(a, b, c, 0, 0, 0);
}

__device__ __forceinline__ void gload_lds16(const unsigned short* g, unsigned short* l) {
  __builtin_amdgcn_global_load_lds((const GLOB_AS void*)g, (LDS_AS void*)l, 16, 0, 0);
}

// ---------------- fused prep: 4x W transpose (blocks 0..4095) + x cvt (4096..6143) ----
__global__ void prep_kernel(const float* __restrict__ x,
                            const float* __restrict__ W0, const float* __restrict__ W1,
                            const float* __restrict__ W2, const float* __restrict__ W3,
                            unsigned short* __restrict__ xb, unsigned short* __restrict__ wt) {
  __shared__ float tile[32][33];
  int blk = blockIdx.x, tid = threadIdx.x;
  if (blk < 4096) {
    int z = blk >> 10, xy = blk & 1023;
    int n0 = (xy & 31) * 32, k0 = (xy >> 5) * 32;
    const float* W = (z == 0) ? W0 : (z == 1) ? W1 : (z == 2) ? W2 : W3;
    unsigned short* dst = wt + z * 1024 * 1024;
    int tx = tid & 31, ty = tid >> 5;  // 32 x 8
#pragma unroll
    for (int j = 0; j < 4; ++j)
      tile[ty + j * 8][tx] = W[(k0 + ty + j * 8) * 1024 + n0 + tx];
    __syncthreads();
#pragma unroll
    for (int j = 0; j < 4; ++j)
      dst[(n0 + ty + j * 8) * 1024 + k0 + tx] = f2b(tile[tx][ty + j * 8]);
  } else {
    int i = ((blk - 4096) * 256 + tid) << 3;
    float4 f0 = *(const float4*)(x + i);
    float4 f1 = *(const float4*)(x + i + 4);
    short8 o;
    o[0] = (short)f2b(f0.x); o[1] = (short)f2b(f0.y); o[2] = (short)f2b(f0.z); o[3] = (short)f2b(f0.w);
    o[4] = (short)f2b(f1.x); o[5] = (short)f2b(f1.y); o[6] = (short)f2b(f1.z); o[7] = (short)f2b(f1.w);
    *(short8*)(xb + i) = o;
  }
}

// ---------------- GEMM0: QKV fused. C[4096,3072] = A[4096,1024] * Bt[3072,1024] ------
__global__ __launch_bounds__(256, 2)
void gemm_kernel(const unsigned short* __restrict__ A,
                 const unsigned short* __restrict__ Bt,
                 unsigned short* __restrict__ q_out,
                 unsigned short* __restrict__ k_out,
                 unsigned short* __restrict__ v_out) {
  const int K = 1024, NBX = 24;
  __shared__ __align__(16) unsigned short As[128 * 32];
  __shared__ __align__(16) unsigned short Bs[128 * 32];
  int tid = threadIdx.x;
  int wave = tid >> 6, lane = tid & 63;
  int wm = wave >> 1, wn = wave & 1;
  int l15 = lane & 15, lg = lane >> 4;

  int bid0 = blockIdx.y * NBX + blockIdx.x;
  int cpx = (NBX * 32) >> 3;
  int swz = (bid0 & 7) * cpx + (bid0 >> 3);
  int m0 = (swz / NBX) * 128, n0 = (swz % NBX) * 128;

  f32x4 acc[4][4] = {};

  int chRow = lane >> 2;
  int chCol = (lane & 3) << 3;
  const unsigned short* gA0 = A  + (m0 + (wave << 5) + chRow) * K + chCol;
  const unsigned short* gA1 = gA0 + 16 * K;
  const unsigned short* gB0 = Bt + (n0 + (wave << 5) + chRow) * K + chCol;
  const unsigned short* gB1 = gB0 + 16 * K;
  unsigned short* lA0 = As + (wave * 2 + 0) * 512;
  unsigned short* lA1 = As + (wave * 2 + 1) * 512;
  unsigned short* lB0 = Bs + (wave * 2 + 0) * 512;
  unsigned short* lB1 = Bs + (wave * 2 + 1) * 512;

  const unsigned short* pa = As + (wm * 64 + l15) * 32 + (lg << 3);
  const unsigned short* pb = Bs + (wn * 64 + l15) * 32 + (lg << 3);

  for (int kt = 0; kt < 32; ++kt) {
    __syncthreads();
    gload_lds16(gA0, lA0); gload_lds16(gA1, lA1);
    gload_lds16(gB0, lB0); gload_lds16(gB1, lB1);
    gA0 += 32; gA1 += 32; gB0 += 32; gB1 += 32;
    __syncthreads();
    short8 a[4], b[4];
#pragma unroll
    for (int mt = 0; mt < 4; ++mt) a[mt] = *(const short8*)(pa + mt * 16 * 32);
#pragma unroll
    for (int nt = 0; nt < 4; ++nt) b[nt] = *(const short8*)(pb + nt * 16 * 32);
#pragma unroll
    for (int mt = 0; mt < 4; ++mt)
#pragma unroll
      for (int nt = 0; nt < 4; ++nt)
        acc[mt][nt] = mfma16(a[mt], b[nt], acc[mt][nt]);
  }

#pragma unroll
  for (int mt = 0; mt < 4; ++mt) {
#pragma unroll
    for (int nt = 0; nt < 4; ++nt) {
      int m = m0 + wm * 64 + mt * 16 + (lg << 2);
      int n = n0 + wn * 64 + nt * 16 + l15;
      int w = n >> 10, nn = n & 1023;
      if (w == 0) {
#pragma unroll
        for (int r = 0; r < 4; ++r)
          q_out[(m + r) * 1024 + nn] = f2b(acc[mt][nt][r]);
      } else if (w == 1) {
#pragma unroll
        for (int r = 0; r < 4; ++r)
          k_out[(m + r) * 1024 + nn] = f2b(acc[mt][nt][r]);
      } else {
        int h = nn >> 6, dh = nn & 63;
        int b = m >> 11, s = m & 2047;
        short4v pk;
#pragma unroll
        for (int r = 0; r < 4; ++r) pk[r] = (short)f2b(acc[mt][nt][r]);
        *(short4v*)(v_out + ((b * 16 + h) * 64 + dh) * 2048 + s) = pk;
      }
    }
  }
}

// ---------------- GEMM2: out proj. out[4096,1024]f32 = A[4096,1024] * Bt[1024,1024] --
// BM=64, BN=128 -> 512 blocks (2/CU). 4 waves: wave covers 32x64 (acc[2][4]).
__global__ __launch_bounds__(256, 2)
void gemm2_kernel(const unsigned short* __restrict__ A,
                  const unsigned short* __restrict__ Bt,
                  float* __restrict__ f_out) {
  const int K = 1024;
  __shared__ __align__(16) unsigned short As[64 * 32];
  __shared__ __align__(16) unsigned short Bs[128 * 32];
  int tid = threadIdx.x;
  int wave = tid >> 6, lane = tid & 63;
  int wm = wave >> 1, wn = wave & 1;
  int l15 = lane & 15, lg = lane >> 4;

  int bid0 = blockIdx.x;                      // 512 blocks
  int swz = (bid0 & 7) * 64 + (bid0 >> 3);    // bijective XCD swizzle
  int m0 = (swz >> 3) * 64, n0 = (swz & 7) * 128;

  f32x4 acc[2][4] = {};

  // staging: 12 chunks (A:4, B:8), 3 per wave
  int chRow = lane >> 2;
  int chCol = (lane & 3) << 3;
  const unsigned short* gp[3];
  unsigned short* lp[3];
#pragma unroll
  for (int j = 0; j < 3; ++j) {
    int c = wave * 3 + j;
    if (c < 4) {
      gp[j] = A + (m0 + c * 16 + chRow) * K + chCol;
      lp[j] = As + c * 512;
    } else {
      int cb = c - 4;
      gp[j] = Bt + (n0 + cb * 16 + chRow) * K + chCol;
      lp[j] = Bs + cb * 512;
    }
  }

  const unsigned short* pa = As + (wm * 32 + l15) * 32 + (lg << 3);
  const unsigned short* pb = Bs + (wn * 64 + l15) * 32 + (lg << 3);

  for (int kt = 0; kt < 32; ++kt) {
    __syncthreads();
    gload_lds16(gp[0], lp[0]); gload_lds16(gp[1], lp[1]); gload_lds16(gp[2], lp[2]);
    gp[0] += 32; gp[1] += 32; gp[2] += 32;
    __syncthreads();
    short8 a[2], b[4];
#pragma unroll
    for (int mt = 0; mt < 2; ++mt) a[mt] = *(const short8*)(pa + mt * 512);
#pragma unroll
    for (int nt = 0; nt < 4; ++nt) b[nt] = *(const short8*)(pb + nt * 512);
#pragma unroll
    for (int mt = 0; mt < 2; ++mt)
#pragma unroll
      for (int nt = 0; nt < 4; ++nt)
        acc[mt][nt] = mfma16(a[mt], b[nt], acc[mt][nt]);
  }

#pragma unroll
  for (int mt = 0; mt < 2; ++mt)
#pragma unroll
    for (int nt = 0; nt < 4; ++nt) {
      int m = m0 + wm * 32 + mt * 16 + (lg << 2);
      int n = n0 + wn * 64 + nt * 16 + l15;
#pragma unroll
      for (int r = 0; r < 4; ++r)
        f_out[(m + r) * 1024 + n] = acc[mt][nt][r];
    }
}

// ---------------- flash attention, LDS-staged K/V, 2-phase pipeline, 8 waves --------
// grid: 512 blocks = bh(32) x qtile(16); 8 waves/block, 16 q-rows/wave.
// K tile [64 kv][64 dh], V tile [64 dh][64 kv] in LDS, XOR-chunk-swizzled (both sides).
// No-max softmax (scores bounded ~+-50, e^s fits f32); row-sum deferred to epilogue.
__global__ __launch_bounds__(512, 4)
void attn_kernel(const unsigned short* __restrict__ qb,
                 const unsigned short* __restrict__ kb,
                 const unsigned short* __restrict__ vt,
                 unsigned short* __restrict__ ob) {
  __shared__ __align__(16) unsigned short Ks[2][4096];
  __shared__ __align__(16) unsigned short Vs[2][4096];
  __shared__ __align__(16) unsigned short plds[8][16][72];
  int tid = threadIdx.x, wave = tid >> 6, lane = tid & 63;
  int l15 = lane & 15, lg = lane >> 4;

  // XCD swizzle: XCD x gets 4 whole bh's (K/V 2MB -> fits per-XCD L2)
  int bid = blockIdx.x;
  int wid = (bid & 7) * 64 + (bid >> 3);
  int bh = wid >> 4, qt = wid & 15;
  int b = bh >> 4, h = bh & 15;
  int q0 = qt * 128 + wave * 16;

  // Q fragments (held for whole kernel)
  const unsigned short* qptr = qb + (b * 2048 + q0 + l15) * 1024 + h * 64 + (lg << 3);
  short8 aq0 = *(const short8*)(qptr);
  short8 aq1 = *(const short8*)(qptr + 32);

  // staging: wave stages rows 8w..8w+7 of K and V tiles (1KB each).
  // lane l -> tile row 8w+(l>>3), LDS slot (l&7) holds global chunk (l&7)^(row&7).
  int srow = lane >> 3;
  int csrc = ((lane & 7) ^ srow) << 3;
  const unsigned short* gK = kb + (b * 2048 + wave * 8 + srow) * 1024 + h * 64 + csrc;
  const unsigned short* gV = vt + (bh * 64 + wave * 8 + srow) * 2048 + csrc;
  unsigned short* lK[2] = { &Ks[0][wave * 512], &Ks[1][wave * 512] };
  unsigned short* lV[2] = { &Vs[0][wave * 512], &Vs[1][wave * 512] };

  // prologue: stage tile 0 into buf 0
  gload_lds16(gK, lK[0]); gload_lds16(gV, lV[0]);
  gK += 65536; gV += 64;

  f32x4 oacc[4] = {};
  float lrun[4] = {};
  const float LOG2E = 1.4426950408889634f;

  for (int t = 0; t < 32; ++t) {
    int buf = t & 1;
    __syncthreads();  // drains own vmcnt -> tile t fully staged; fences prev LDS reads
    if (t < 31) {
      gload_lds16(gK, lK[buf ^ 1]); gload_lds16(gV, lV[buf ^ 1]);
      gK += 65536; gV += 64;
    }

    const unsigned short* Kb = &Ks[buf][0];
    const unsigned short* Vb = &Vs[buf][0];

    // QK^T: 16x64 scores
    f32x4 s[4];
#pragma unroll
    for (int nt = 0; nt < 4; ++nt) {
      int row = nt * 16 + l15, x = row & 7;
      short8 bk0 = *(const short8*)(Kb + row * 64 + ((lg ^ x) << 3));
      short8 bk1 = *(const short8*)(Kb + row * 64 + (((4 + lg) ^ x) << 3));
      f32x4 z = {};
      z = mfma16(aq0, bk0, z);
      z = mfma16(aq1, bk1, z);
      s[nt] = z;
    }

    // P = e^s rounded to bf16; partial row-sums of rounded values
#pragma unroll
    for (int nt = 0; nt < 4; ++nt)
#pragma unroll
      for (int r = 0; r < 4; ++r) {
        float p = exp2_hw(s[nt][r] * LOG2E);
        unsigned short pbf = f2b(p);
        plds[wave][(lg << 2) + r][nt * 16 + l15] = pbf;
        lrun[r] += b2f(pbf);
      }

    // PV: A = P from LDS, B = V^T rows from swizzled V tile
    short8 pa0 = *(const short8*)&plds[wave][l15][(lg << 3)];
    short8 pa1 = *(const short8*)&plds[wave][l15][32 + (lg << 3)];
#pragma unroll
    for (int nt = 0; nt < 4; ++nt) {
      int row = nt * 16 + l15, x = row & 7;
      short8 bv0 = *(const short8*)(Vb + row * 64 + ((lg ^ x) << 3));
      short8 bv1 = *(const short8*)(Vb + row * 64 + (((4 + lg) ^ x) << 3));
      oacc[nt] = mfma16(pa0, bv0, oacc[nt]);
      oacc[nt] = mfma16(pa1, bv1, oacc[nt]);
    }
  }

  // epilogue: row-sum reduce across 16-lane kv groups, normalize, store
  float inv[4];
#pragma unroll
  for (int r = 0; r < 4; ++r) {
    float ssum = lrun[r];
    ssum += __shfl_xor(ssum, 1);
    ssum += __shfl_xor(ssum, 2);
    ssum += __shfl_xor(ssum, 4);
    ssum += __shfl_xor(ssum, 8);
    inv[r] = 1.f / ssum;
  }
#pragma unroll
  for (int nt = 0; nt < 4; ++nt)
#pragma unroll
    for (int r = 0; r < 4; ++r)
      ob[(bh * 2048 + q0 + (lg << 2) + r) * 64 + nt * 16 + l15] = f2b(oacc[nt][r] * inv[r]);
}

extern "C" void kernel_launch(void* const* d_in, const int* in_sizes, int n_in,
                              void* d_out, int out_size, void* d_ws, size_t ws_size,
                              hipStream_t stream) {
  (void)in_sizes; (void)n_in; (void)out_size; (void)ws_size;
  const float* x  = (const float*)d_in[0];
  const float* Wq = (const float*)d_in[1];
  const float* Wk = (const float*)d_in[2];
  const float* Wv = (const float*)d_in[3];
  const float* Wo = (const float*)d_in[4];
  float* out = (float*)d_out;

  unsigned short* ws = (unsigned short*)d_ws;
  const int MB4 = 4 * 1024 * 1024;
  unsigned short* xb = ws;
  unsigned short* wt = xb + MB4;
  unsigned short* qb = wt + MB4;
  unsigned short* kb = qb + MB4;
  unsigned short* vt = kb + MB4;
  unsigned short* cb = vt + MB4;

  prep_kernel<<<6144, 256, 0, stream>>>(x, Wq, Wk, Wv, Wo, xb, wt);
  gemm_kernel<<<dim3(24, 32), 256, 0, stream>>>(xb, wt, qb, kb, vt);
  attn_kernel<<<512, 512, 0, stream>>>(qb, kb, vt, cb);
  gemm2_kernel<<<512, 256, 0, stream>>>(cb, wt + 3 * 1024 * 1024, out);
}